// Round 9
// baseline (740.873 us; speedup 1.0000x reference)
//
#include <hip/hip_runtime.h>
#include <hip/hip_bf16.h>
#include <math.h>

// Problem constants
#define S_LEN  2048
#define BATCH  4
#define NHEAD  16
#define HDIM   64
#define DMODEL 1024
#define NTOK   (BATCH * S_LEN)   // 8192 tokens
#define BHEADS (BATCH * NHEAD)   // 64

typedef __attribute__((ext_vector_type(8))) short bfrag;   // 8 bf16 (4 VGPRs) MFMA A/B frag
typedef __attribute__((ext_vector_type(4))) float f32x4;   // MFMA C/D frag
typedef __attribute__((ext_vector_type(4))) ushort u16x4;

__device__ inline ushort f2bf(float f) {
  union { float f; unsigned u; } v; v.f = f;
  unsigned r = (v.u + 0x7FFFu + ((v.u >> 16) & 1u)) >> 16;  // RNE
  return (ushort)r;
}

// 2-op bf16 round (half-up; differs from RNE only on exact ties)
__device__ inline ushort bfh(float f) {
  union { float f; unsigned u; } v; v.f = f;
  return (ushort)((v.u + 0x8000u) >> 16);
}

__device__ inline void gload_lds16(const void* g, void* lds) {
  __builtin_amdgcn_global_load_lds(
      (const __attribute__((address_space(1))) unsigned int*)g,
      (__attribute__((address_space(3))) unsigned int*)lds, 16, 0, 0);
}

#define SBAR() __builtin_amdgcn_sched_barrier(0)

// ---------------------------------------------------------------------------
// fp32 -> bf16 conversion for the three input activations
__global__ __launch_bounds__(256) void convert_qkv(
    const float* xq, const float* xk, const float* xv,
    ushort* oq, ushort* ok, ushort* ov) {
  const float* src = (blockIdx.y == 0) ? xq : (blockIdx.y == 1) ? xk : xv;
  ushort* dst      = (blockIdx.y == 0) ? oq : (blockIdx.y == 1) ? ok : ov;
  const int n4 = NTOK * DMODEL / 4;
  for (int i = blockIdx.x * blockDim.x + threadIdx.x; i < n4;
       i += gridDim.x * blockDim.x) {
    float4 f = reinterpret_cast<const float4*>(src)[i];
    ushort4 o;
    o.x = f2bf(f.x); o.y = f2bf(f.y); o.z = f2bf(f.z); o.w = f2bf(f.w);
    reinterpret_cast<ushort4*>(dst)[i] = o;
  }
}

// W [K=1024][N=1024] fp32  ->  Wt [N][K] bf16 (so GEMM B-fragments are contiguous)
__global__ __launch_bounds__(256) void wtrans(const float* w, ushort* wt) {
  __shared__ float t[64][65];
  const int k0 = (blockIdx.x >> 4) * 64;
  const int n0 = (blockIdx.x & 15) * 64;
  for (int i = threadIdx.x; i < 4096; i += 256) {
    int r = i >> 6, c = i & 63;
    t[r][c] = w[(size_t)(k0 + r) * DMODEL + n0 + c];
  }
  __syncthreads();
  for (int i = threadIdx.x; i < 4096; i += 256) {
    int r = i >> 6, c = i & 63;
    wt[(size_t)(n0 + r) * DMODEL + k0 + c] = f2bf(t[c][r]);
  }
}

// V [BH][S][64] bf16 -> Vt [BH][64][S] bf16 (so PV B-fragments are contiguous)
__global__ __launch_bounds__(256) void vtrans(const ushort* v, ushort* vt) {
  __shared__ ushort t[64][65];
  const int bh = blockIdx.y;
  const int s0 = blockIdx.x * 64;
  const ushort* vb = v  + (size_t)bh * S_LEN * HDIM;
  ushort*       vo = vt + (size_t)bh * HDIM * S_LEN;
  for (int i = threadIdx.x; i < 4096; i += 256) {
    int r = i >> 6, c = i & 63;
    t[r][c] = vb[(size_t)(s0 + r) * HDIM + c];
  }
  __syncthreads();
  for (int i = threadIdx.x; i < 4096; i += 256) {
    int r = i >> 6, c = i & 63;               // r = head-dim, c = seq offset
    vo[(size_t)r * S_LEN + s0 + c] = t[c][r];
  }
}

// ---------------------------------------------------------------------------
// C = A[M,K] @ Bt[N,K]^T + bias.  128x128 tile, BK=32, 4 waves, 4x4 frags/wave.
template <int MODE>
__global__ __launch_bounds__(256) void gemm_bt(
    const ushort* A0, const ushort* A1, const ushort* A2,
    const ushort* B0, const ushort* B1, const ushort* B2,
    const float* c0, const float* c1, const float* c2,
    void* o0, void* o1, void* o2, int M, int N, int K) {
  const int z = blockIdx.z;
  const ushort* A  = z == 0 ? A0 : z == 1 ? A1 : A2;
  const ushort* Bt = z == 0 ? B0 : z == 1 ? B1 : B2;
  const float* bias = z == 0 ? c0 : z == 1 ? c1 : c2;
  void* dst = z == 0 ? o0 : z == 1 ? o1 : o2;

  __shared__ __align__(16) ushort As[128][32];
  __shared__ __align__(16) ushort Bs[128][32];
  const int tid  = threadIdx.x;
  const int wid  = tid >> 6;
  const int l15  = tid & 15;
  const int lh   = (tid & 63) >> 4;
  const int row0 = blockIdx.x * 128;
  const int col0 = blockIdx.y * 128;
  const int wr   = (wid >> 1) * 64;
  const int wc   = (wid & 1) * 64;

  f32x4 acc[4][4] = {};

  for (int kt = 0; kt < K; kt += 32) {
#pragma unroll
    for (int j = 0; j < 2; ++j) {
      const int toff = (j * 256 + tid) * 16;  // linear byte offset in the 8 KB tile
      const int r    = toff >> 6;             // 64 B per tile row
      const int cb   = toff & 63;
      gload_lds16(A + (size_t)(row0 + r) * K + kt + (cb >> 1),
                  (char*)(&As[0][0]) + (j * 256 + wid * 64) * 16);
      gload_lds16(Bt + (size_t)(col0 + r) * K + kt + (cb >> 1),
                  (char*)(&Bs[0][0]) + (j * 256 + wid * 64) * 16);
    }
    __syncthreads();
    bfrag av[4], bv[4];
#pragma unroll
    for (int m = 0; m < 4; ++m) av[m] = *(const bfrag*)&As[wr + m * 16 + l15][lh * 8];
#pragma unroll
    for (int n = 0; n < 4; ++n) bv[n] = *(const bfrag*)&Bs[wc + n * 16 + l15][lh * 8];
#pragma unroll
    for (int m = 0; m < 4; ++m)
#pragma unroll
      for (int n = 0; n < 4; ++n)
        acc[m][n] = __builtin_amdgcn_mfma_f32_16x16x32_bf16(av[m], bv[n], acc[m][n], 0, 0, 0);
    __syncthreads();
  }

#pragma unroll
  for (int m = 0; m < 4; ++m) {
#pragma unroll
    for (int n = 0; n < 4; ++n) {
#pragma unroll
      for (int r = 0; r < 4; ++r) {
        const int grow = row0 + wr + m * 16 + lh * 4 + r;   // token / output row
        const int gcol = col0 + wc + n * 16 + l15;          // output channel
        const float v = acc[m][n][r] + bias[gcol];
        if (MODE == 0) {
          ((float*)dst)[(size_t)grow * N + gcol] = v;
        } else {
          const size_t o = (((size_t)(grow >> 11) * NHEAD + (gcol >> 6)) * S_LEN +
                            (grow & 2047)) * HDIM + (gcol & 63);
          ((ushort*)dst)[o] = f2bf(v);
        }
      }
    }
  }
}

// ---------------------------------------------------------------------------
// Fused attention v8: identical to v7 except the batched attn stores go
// THROUGH L2 (nontemporal dropped). L2 aggregates the 256B runs into full-line
// streaming evictions (fillBuffer-style, ~6.5TB/s) instead of raw 256B bursts
// at the controller (~3TB/s). K/V eviction cost is absorbed by L3.
__global__ __launch_bounds__(256) void attn_kernel(
    const ushort* Q, const ushort* K, const ushort* Vt, float* attn, ushort* ctx) {
  // XCD swizzle: all 32 q-tiles of one head on one XCD (K/V stay L2-resident)
  const int b0    = blockIdx.x;          // 0..2047
  const int xcd   = b0 & 7;
  const int inner = b0 >> 3;             // 0..255
  const int bh    = xcd + ((inner >> 5) << 3);   // batch*head 0..63
  const int qt    = inner & 31;
  const int b  = bh >> 4;
  const int h  = bh & 15;
  const int q0 = qt * 64;
  const int wid  = threadIdx.x >> 6;
  const int lane = threadIdx.x & 63;
  const int l15  = lane & 15;
  const int lh   = lane >> 4;

  const ushort* Qb = Q  + ((size_t)bh * S_LEN + q0 + wid * 16) * HDIM;
  const ushort* Kb = K  + (size_t)bh * S_LEN * HDIM;
  const ushort* Vb = Vt + (size_t)bh * HDIM * S_LEN;

  __shared__ __align__(16) ushort Ks[3][32 * 64];
  __shared__ __align__(16) ushort Vs[3][64 * 32];
  __shared__ __align__(16) ushort Plds[4][16][40];
  __shared__ __align__(16) float  Pool[4][16][66];   // per-wave P staging (f32)

  const int krow   = threadIdx.x >> 3;
  const int kchk_s = (threadIdx.x & 7) ^ (krow & 7);
  const int vrow   = threadIdx.x >> 2;
  const int vchk_s = (threadIdx.x & 3) ^ (vrow & 3);

  const int ksw0 = ((lh ^ (l15 & 7)) * 8);
  const int ksw1 = (((lh + 4) ^ (l15 & 7)) * 8);
  const int vsw  = ((lh ^ (l15 & 3)) * 8);

  const bfrag qf0 = *(const bfrag*)&Qb[(size_t)l15 * HDIM + lh * 8];
  const bfrag qf1 = *(const bfrag*)&Qb[(size_t)l15 * HDIM + 32 + lh * 8];

  const float c = 0.125f * 1.44269504089f;  // log2(e)/sqrt(HDIM)
  const int NT = S_LEN / 32;                // 64 tiles

  // ---- Pass 1: l[q] = sum_k exp2(s*c); S^T layout: lane q=l15, k=4*lh+r ----
  gload_lds16(Kb + (size_t)(0 * 32 + krow) * HDIM + kchk_s * 8, (char*)&Ks[0][0] + wid * 1024);
  gload_lds16(Kb + (size_t)(1 * 32 + krow) * HDIM + kchk_s * 8, (char*)&Ks[1][0] + wid * 1024);
  SBAR();
  asm volatile("s_waitcnt vmcnt(1)" ::: "memory");  // own g0 landed (qf over-waited)
  __builtin_amdgcn_s_barrier();
  SBAR();

  int cur = 0;
  float lr = 0.f;
  for (int t = 0; t < NT; ++t) {
    if (t + 2 < NT) {
      int s2 = cur + 2; if (s2 >= 3) s2 -= 3;
      gload_lds16(Kb + (size_t)((t + 2) * 32 + krow) * HDIM + kchk_s * 8,
                  (char*)&Ks[s2][0] + wid * 1024);
    }
    const bfrag ca0 = *(const bfrag*)&Ks[cur][l15 * 64 + ksw0];
    const bfrag ca1 = *(const bfrag*)&Ks[cur][l15 * 64 + ksw1];
    const bfrag cb0 = *(const bfrag*)&Ks[cur][(16 + l15) * 64 + ksw0];
    const bfrag cb1 = *(const bfrag*)&Ks[cur][(16 + l15) * 64 + ksw1];
    f32x4 sa = {}, sb = {};
    __builtin_amdgcn_s_setprio(1);
    sa = __builtin_amdgcn_mfma_f32_16x16x32_bf16(ca0, qf0, sa, 0, 0, 0);
    sa = __builtin_amdgcn_mfma_f32_16x16x32_bf16(ca1, qf1, sa, 0, 0, 0);
    sb = __builtin_amdgcn_mfma_f32_16x16x32_bf16(cb0, qf0, sb, 0, 0, 0);
    sb = __builtin_amdgcn_mfma_f32_16x16x32_bf16(cb1, qf1, sb, 0, 0, 0);
    __builtin_amdgcn_s_setprio(0);
#pragma unroll
    for (int r = 0; r < 4; ++r)
      lr += exp2f(sa[r] * c) + exp2f(sb[r] * c);
    if (t < NT - 1) {
      SBAR();
      if (t < NT - 2) asm volatile("s_waitcnt vmcnt(1)" ::: "memory");
      else            asm volatile("s_waitcnt vmcnt(0)" ::: "memory");
      __builtin_amdgcn_s_barrier();
      SBAR();
    }
    cur = cur + 1; if (cur >= 3) cur -= 3;
  }
  // lanes {l15, +16, +32, +48} hold partials of the same q row
  lr += __shfl_xor(lr, 16);
  lr += __shfl_xor(lr, 32);
  const float linv = __builtin_amdgcn_rcpf(lr);

  // ---- inter-pass barrier: pass-2 stage DMAs issued only after release ----
  SBAR();
  __builtin_amdgcn_s_barrier();
  SBAR();

  // ---- Pass 2: recompute, normalize, pool P, batched L2-routed stores, PV ----
  f32x4 cacc[4] = {};

  gload_lds16(Kb + (size_t)(0 * 32 + krow) * HDIM + kchk_s * 8, (char*)&Ks[0][0] + wid * 1024);
  gload_lds16(Vb + (size_t)vrow * S_LEN + 0  + vchk_s * 8,      (char*)&Vs[0][0] + wid * 1024);
  gload_lds16(Kb + (size_t)(1 * 32 + krow) * HDIM + kchk_s * 8, (char*)&Ks[1][0] + wid * 1024);
  gload_lds16(Vb + (size_t)vrow * S_LEN + 32 + vchk_s * 8,      (char*)&Vs[1][0] + wid * 1024);
  SBAR();
  asm volatile("s_waitcnt vmcnt(2)" ::: "memory");  // own g0 pair landed; g1 in flight
  __builtin_amdgcn_s_barrier();
  SBAR();

  cur = 0;
  for (int t = 0; t < NT; ++t) {
    const int k0 = t * 32;
    if (t + 2 < NT) {
      int s2 = cur + 2; if (s2 >= 3) s2 -= 3;
      gload_lds16(Kb + (size_t)(k0 + 64 + krow) * HDIM + kchk_s * 8,
                  (char*)&Ks[s2][0] + wid * 1024);
      gload_lds16(Vb + (size_t)vrow * S_LEN + k0 + 64 + vchk_s * 8,
                  (char*)&Vs[s2][0] + wid * 1024);
    }
    const bfrag ca0 = *(const bfrag*)&Ks[cur][l15 * 64 + ksw0];
    const bfrag ca1 = *(const bfrag*)&Ks[cur][l15 * 64 + ksw1];
    const bfrag cb0 = *(const bfrag*)&Ks[cur][(16 + l15) * 64 + ksw0];
    const bfrag cb1 = *(const bfrag*)&Ks[cur][(16 + l15) * 64 + ksw1];
    const bfrag vf0 = *(const bfrag*)&Vs[cur][(0 * 16 + l15) * 32 + vsw];
    const bfrag vf1 = *(const bfrag*)&Vs[cur][(1 * 16 + l15) * 32 + vsw];
    const bfrag vf2 = *(const bfrag*)&Vs[cur][(2 * 16 + l15) * 32 + vsw];
    const bfrag vf3 = *(const bfrag*)&Vs[cur][(3 * 16 + l15) * 32 + vsw];

    f32x4 sa = {}, sb = {};
    __builtin_amdgcn_s_setprio(1);
    sa = __builtin_amdgcn_mfma_f32_16x16x32_bf16(ca0, qf0, sa, 0, 0, 0);
    sa = __builtin_amdgcn_mfma_f32_16x16x32_bf16(ca1, qf1, sa, 0, 0, 0);
    sb = __builtin_amdgcn_mfma_f32_16x16x32_bf16(cb0, qf0, sb, 0, 0, 0);
    sb = __builtin_amdgcn_mfma_f32_16x16x32_bf16(cb1, qf1, sb, 0, 0, 0);
    __builtin_amdgcn_s_setprio(0);

    f32x4 pa, pb;
#pragma unroll
    for (int r = 0; r < 4; ++r) pa[r] = exp2f(sa[r] * c) * linv;
#pragma unroll
    for (int r = 0; r < 4; ++r) pb[r] = exp2f(sb[r] * c) * linv;

    // pool P (f32, wave-private rows): parity halves of the 64-col pair window
    const int pcol = (t & 1) * 32;
    *(f32x4*)&Pool[wid][l15][pcol + lh * 4]      = pa;
    *(f32x4*)&Pool[wid][l15][pcol + 16 + lh * 4] = pb;

    u16x4 ua = {bfh(pa[0]), bfh(pa[1]), bfh(pa[2]), bfh(pa[3])};
    u16x4 ub = {bfh(pb[0]), bfh(pb[1]), bfh(pb[2]), bfh(pb[3])};
    *(u16x4*)&Plds[wid][l15][lh * 4]      = ua;
    *(u16x4*)&Plds[wid][l15][16 + lh * 4] = ub;

    const bfrag pf = *(const bfrag*)&Plds[wid][l15][lh * 8];
    __builtin_amdgcn_s_setprio(1);
    cacc[0] = __builtin_amdgcn_mfma_f32_16x16x32_bf16(pf, vf0, cacc[0], 0, 0, 0);
    cacc[1] = __builtin_amdgcn_mfma_f32_16x16x32_bf16(pf, vf1, cacc[1], 0, 0, 0);
    cacc[2] = __builtin_amdgcn_mfma_f32_16x16x32_bf16(pf, vf2, cacc[2], 0, 0, 0);
    cacc[3] = __builtin_amdgcn_mfma_f32_16x16x32_bf16(pf, vf3, cacc[3], 0, 0, 0);
    __builtin_amdgcn_s_setprio(0);

    if (t & 1) {
      // drain the wave's 16x64 P window as 4 x 1KB stores (256B runs), via L2.
      const int kb = (t - 1) * 32;
#pragma unroll
      for (int i = 0; i < 4; ++i) {
        const int rw = i * 4 + (lane >> 4);            // row within wave slice
        const f32x4 v = *(const f32x4*)&Pool[wid][rw][(lane & 15) * 4];
        float* dst = attn + ((size_t)bh * S_LEN + q0 + wid * 16 + rw) * S_LEN +
                     kb + (lane & 15) * 4;
        *(f32x4*)dst = v;
      }
    }

    if (t < NT - 1) {
      SBAR();
      // newer-than-g_{t+1}: stores(4 per pair) + g_{t+2}(2) = 6 uniformly.
      if (t < NT - 2) asm volatile("s_waitcnt vmcnt(6)" ::: "memory");
      else            asm volatile("s_waitcnt vmcnt(4)" ::: "memory");
      __builtin_amdgcn_s_barrier();
      SBAR();
    }
    cur = cur + 1; if (cur >= 3) cur -= 3;
  }

  // ctx in [B,S,H*64] bf16 so the output GEMM reads contiguous rows
#pragma unroll
  for (int n = 0; n < 4; ++n) {
#pragma unroll
    for (int r = 0; r < 4; ++r) {
      const size_t tok = (size_t)b * S_LEN + q0 + wid * 16 + lh * 4 + r;
      ctx[tok * DMODEL + h * HDIM + n * 16 + l15] = f2bf(cacc[n][r]);
    }
  }
}

// ---------------------------------------------------------------------------
extern "C" void kernel_launch(void* const* d_in, const int* in_sizes, int n_in,
                              void* d_out, int out_size, void* d_ws, size_t ws_size,
                              hipStream_t stream) {
  const float* Xq = (const float*)d_in[0];
  const float* Xk = (const float*)d_in[1];
  const float* Xv = (const float*)d_in[2];
  const float* Wq = (const float*)d_in[3];
  const float* bq = (const float*)d_in[4];
  const float* Wk = (const float*)d_in[5];
  const float* bk = (const float*)d_in[6];
  const float* Wv = (const float*)d_in[7];
  const float* bv = (const float*)d_in[8];
  const float* Wo = (const float*)d_in[9];
  const float* bo = (const float*)d_in[10];

  float* out  = (float*)d_out;                       // [B,S,D]
  float* attn = out + (size_t)NTOK * DMODEL;         // [B,H,S,S]

  char* ws = (char*)d_ws;
  const size_t XB = (size_t)NTOK * DMODEL * 2;       // 16 MB bf16 activation
  const size_t WB = (size_t)DMODEL * DMODEL * 2;     // 2 MB bf16 weight
  ushort* xq  = (ushort*)(ws);
  ushort* xk  = (ushort*)(ws + XB);
  ushort* xv  = (ushort*)(ws + 2 * XB);
  ushort* wqt = (ushort*)(ws + 3 * XB);
  ushort* wkt = (ushort*)(ws + 3 * XB + WB);
  ushort* wvt = (ushort*)(ws + 3 * XB + 2 * WB);
  ushort* wot = (ushort*)(ws + 3 * XB + 3 * WB);
  ushort* qh  = (ushort*)(ws + 3 * XB + 4 * WB);          // [BH,S,64]
  ushort* kh  = (ushort*)(ws + 4 * XB + 4 * WB);
  ushort* vh  = (ushort*)(ws + 5 * XB + 4 * WB);
  ushort* vt  = (ushort*)(ws + 6 * XB + 4 * WB);          // [BH,64,S]
  ushort* ctx = (ushort*)(ws + 7 * XB + 4 * WB);          // [B,S,1024]

  convert_qkv<<<dim3(1024, 3), 256, 0, stream>>>(Xq, Xk, Xv, xq, xk, xv);
  wtrans<<<256, 256, 0, stream>>>(Wq, wqt);
  wtrans<<<256, 256, 0, stream>>>(Wk, wkt);
  wtrans<<<256, 256, 0, stream>>>(Wv, wvt);
  wtrans<<<256, 256, 0, stream>>>(Wo, wot);

  // Q,K,V projections: M=8192, N=1024, K=1024, outputs scattered to head layout
  gemm_bt<1><<<dim3(64, 8, 3), 256, 0, stream>>>(
      xq, xk, xv, wqt, wkt, wvt, bq, bk, bv,
      (void*)qh, (void*)kh, (void*)vh, NTOK, DMODEL, DMODEL);

  vtrans<<<dim3(32, BHEADS), 256, 0, stream>>>(vh, vt);

  attn_kernel<<<dim3(S_LEN / 64 * BHEADS), 256, 0, stream>>>(qh, kh, vt, attn, ctx);

  // out = ctx @ Wo^T + bo (fp32 into d_out)
  gemm_bt<0><<<dim3(64, 8, 1), 256, 0, stream>>>(
      ctx, ctx, ctx, wot, wot, wot, bo, bo, bo,
      (void*)out, (void*)out, (void*)out, NTOK, DMODEL, DMODEL);
}

// Round 10
// 479.824 us; speedup vs baseline: 1.5441x; 1.5441x over previous
//
#include <hip/hip_runtime.h>
#include <hip/hip_bf16.h>
#include <math.h>

// Problem constants
#define S_LEN  2048
#define BATCH  4
#define NHEAD  16
#define HDIM   64
#define DMODEL 1024
#define NTOK   (BATCH * S_LEN)   // 8192 tokens
#define BHEADS (BATCH * NHEAD)   // 64

typedef __attribute__((ext_vector_type(8))) short bfrag;   // 8 bf16 (4 VGPRs) MFMA A/B frag
typedef __attribute__((ext_vector_type(4))) float f32x4;   // MFMA C/D frag
typedef __attribute__((ext_vector_type(4))) ushort u16x4;

__device__ inline ushort f2bf(float f) {
  union { float f; unsigned u; } v; v.f = f;
  unsigned r = (v.u + 0x7FFFu + ((v.u >> 16) & 1u)) >> 16;  // RNE
  return (ushort)r;
}

// 2-op bf16 round (half-up; differs from RNE only on exact ties)
__device__ inline ushort bfh(float f) {
  union { float f; unsigned u; } v; v.f = f;
  return (ushort)((v.u + 0x8000u) >> 16);
}

__device__ inline void gload_lds16(const void* g, void* lds) {
  __builtin_amdgcn_global_load_lds(
      (const __attribute__((address_space(1))) unsigned int*)g,
      (__attribute__((address_space(3))) unsigned int*)lds, 16, 0, 0);
}

#define SBAR() __builtin_amdgcn_sched_barrier(0)

// ---------------------------------------------------------------------------
// Fused prep: y in {0,1,2} -> fp32->bf16 convert of Q/K/V activations;
// y == 3 -> all four weight transposes (W [K][N] fp32 -> Wt [N][K] bf16).
__global__ __launch_bounds__(256) void prep_kernel(
    const float* xq, const float* xk, const float* xv,
    ushort* oq, ushort* ok, ushort* ov,
    const float* w0, const float* w1, const float* w2, const float* w3,
    ushort* t0, ushort* t1, ushort* t2, ushort* t3) {
  if (blockIdx.y < 3) {
    const float* src = (blockIdx.y == 0) ? xq : (blockIdx.y == 1) ? xk : xv;
    ushort* dst      = (blockIdx.y == 0) ? oq : (blockIdx.y == 1) ? ok : ov;
    const int n4 = NTOK * DMODEL / 4;
    for (int i = blockIdx.x * blockDim.x + threadIdx.x; i < n4;
         i += gridDim.x * blockDim.x) {
      float4 f = reinterpret_cast<const float4*>(src)[i];
      ushort4 o;
      o.x = f2bf(f.x); o.y = f2bf(f.y); o.z = f2bf(f.z); o.w = f2bf(f.w);
      reinterpret_cast<ushort4*>(dst)[i] = o;
    }
  } else {
    __shared__ float t[64][65];
    const int widx = blockIdx.x >> 8;          // which weight
    const int bx   = blockIdx.x & 255;
    const float* w = widx == 0 ? w0 : widx == 1 ? w1 : widx == 2 ? w2 : w3;
    ushort*     wt = widx == 0 ? t0 : widx == 1 ? t1 : widx == 2 ? t2 : t3;
    const int k0 = (bx >> 4) * 64;
    const int n0 = (bx & 15) * 64;
    for (int i = threadIdx.x; i < 4096; i += 256) {
      int r = i >> 6, c = i & 63;
      t[r][c] = w[(size_t)(k0 + r) * DMODEL + n0 + c];
    }
    __syncthreads();
    for (int i = threadIdx.x; i < 4096; i += 256) {
      int r = i >> 6, c = i & 63;
      wt[(size_t)(n0 + r) * DMODEL + k0 + c] = f2bf(t[c][r]);
    }
  }
}

// V [BH][S][64] bf16 -> Vt [BH][64][S] bf16 (so PV B-fragments are contiguous)
__global__ __launch_bounds__(256) void vtrans(const ushort* v, ushort* vt) {
  __shared__ ushort t[64][65];
  const int bh = blockIdx.y;
  const int s0 = blockIdx.x * 64;
  const ushort* vb = v  + (size_t)bh * S_LEN * HDIM;
  ushort*       vo = vt + (size_t)bh * HDIM * S_LEN;
  for (int i = threadIdx.x; i < 4096; i += 256) {
    int r = i >> 6, c = i & 63;
    t[r][c] = vb[(size_t)(s0 + r) * HDIM + c];
  }
  __syncthreads();
  for (int i = threadIdx.x; i < 4096; i += 256) {
    int r = i >> 6, c = i & 63;               // r = head-dim, c = seq offset
    vo[(size_t)r * S_LEN + s0 + c] = t[c][r];
  }
}

// ---------------------------------------------------------------------------
// C = A[M,K] @ Bt[N,K]^T + bias.  128x128 tile, BK=32, 4 waves, 4x4 frags/wave.
template <int MODE>
__global__ __launch_bounds__(256) void gemm_bt(
    const ushort* A0, const ushort* A1, const ushort* A2,
    const ushort* B0, const ushort* B1, const ushort* B2,
    const float* c0, const float* c1, const float* c2,
    void* o0, void* o1, void* o2, int M, int N, int K) {
  const int z = blockIdx.z;
  const ushort* A  = z == 0 ? A0 : z == 1 ? A1 : A2;
  const ushort* Bt = z == 0 ? B0 : z == 1 ? B1 : B2;
  const float* bias = z == 0 ? c0 : z == 1 ? c1 : c2;
  void* dst = z == 0 ? o0 : z == 1 ? o1 : o2;

  __shared__ __align__(16) ushort As[128][32];
  __shared__ __align__(16) ushort Bs[128][32];
  const int tid  = threadIdx.x;
  const int wid  = tid >> 6;
  const int l15  = tid & 15;
  const int lh   = (tid & 63) >> 4;
  const int row0 = blockIdx.x * 128;
  const int col0 = blockIdx.y * 128;
  const int wr   = (wid >> 1) * 64;
  const int wc   = (wid & 1) * 64;

  f32x4 acc[4][4] = {};

  for (int kt = 0; kt < K; kt += 32) {
#pragma unroll
    for (int j = 0; j < 2; ++j) {
      const int toff = (j * 256 + tid) * 16;  // linear byte offset in the 8 KB tile
      const int r    = toff >> 6;             // 64 B per tile row
      const int cb   = toff & 63;
      gload_lds16(A + (size_t)(row0 + r) * K + kt + (cb >> 1),
                  (char*)(&As[0][0]) + (j * 256 + wid * 64) * 16);
      gload_lds16(Bt + (size_t)(col0 + r) * K + kt + (cb >> 1),
                  (char*)(&Bs[0][0]) + (j * 256 + wid * 64) * 16);
    }
    __syncthreads();
    bfrag av[4], bv[4];
#pragma unroll
    for (int m = 0; m < 4; ++m) av[m] = *(const bfrag*)&As[wr + m * 16 + l15][lh * 8];
#pragma unroll
    for (int n = 0; n < 4; ++n) bv[n] = *(const bfrag*)&Bs[wc + n * 16 + l15][lh * 8];
#pragma unroll
    for (int m = 0; m < 4; ++m)
#pragma unroll
      for (int n = 0; n < 4; ++n)
        acc[m][n] = __builtin_amdgcn_mfma_f32_16x16x32_bf16(av[m], bv[n], acc[m][n], 0, 0, 0);
    __syncthreads();
  }

#pragma unroll
  for (int m = 0; m < 4; ++m) {
#pragma unroll
    for (int n = 0; n < 4; ++n) {
#pragma unroll
      for (int r = 0; r < 4; ++r) {
        const int grow = row0 + wr + m * 16 + lh * 4 + r;   // token / output row
        const int gcol = col0 + wc + n * 16 + l15;          // output channel
        const float v = acc[m][n][r] + bias[gcol];
        if (MODE == 0) {
          ((float*)dst)[(size_t)grow * N + gcol] = v;
        } else {
          const size_t o = (((size_t)(grow >> 11) * NHEAD + (gcol >> 6)) * S_LEN +
                            (grow & 2047)) * HDIM + (gcol & 63);
          ((ushort*)dst)[o] = f2bf(v);
        }
      }
    }
  }
}

// ---------------------------------------------------------------------------
// Fused attention (R8 structure, best known): wave-private f32 Pool batches P
// into 256B-run nontemporal stores (4 x dwordx4 per 2 k-tiles); nt keeps the
// 1.07GB write-once stream out of L2/L3 (R9 showed L2-routing thrashes -230us).
// Ring-3 K/V staging, counted vmcnt barriers.
__global__ __launch_bounds__(256) void attn_kernel(
    const ushort* Q, const ushort* K, const ushort* Vt, float* attn, ushort* ctx) {
  // XCD swizzle: all 32 q-tiles of one head on one XCD (K/V stay L2-resident)
  const int b0    = blockIdx.x;          // 0..2047
  const int xcd   = b0 & 7;
  const int inner = b0 >> 3;             // 0..255
  const int bh    = xcd + ((inner >> 5) << 3);   // batch*head 0..63
  const int qt    = inner & 31;
  const int b  = bh >> 4;
  const int h  = bh & 15;
  const int q0 = qt * 64;
  const int wid  = threadIdx.x >> 6;
  const int lane = threadIdx.x & 63;
  const int l15  = lane & 15;
  const int lh   = lane >> 4;

  const ushort* Qb = Q  + ((size_t)bh * S_LEN + q0 + wid * 16) * HDIM;
  const ushort* Kb = K  + (size_t)bh * S_LEN * HDIM;
  const ushort* Vb = Vt + (size_t)bh * HDIM * S_LEN;

  __shared__ __align__(16) ushort Ks[3][32 * 64];
  __shared__ __align__(16) ushort Vs[3][64 * 32];
  __shared__ __align__(16) ushort Plds[4][16][40];
  __shared__ __align__(16) float  Pool[4][16][66];   // per-wave P staging (f32)

  const int krow   = threadIdx.x >> 3;
  const int kchk_s = (threadIdx.x & 7) ^ (krow & 7);
  const int vrow   = threadIdx.x >> 2;
  const int vchk_s = (threadIdx.x & 3) ^ (vrow & 3);

  const int ksw0 = ((lh ^ (l15 & 7)) * 8);
  const int ksw1 = (((lh + 4) ^ (l15 & 7)) * 8);
  const int vsw  = ((lh ^ (l15 & 3)) * 8);

  const bfrag qf0 = *(const bfrag*)&Qb[(size_t)l15 * HDIM + lh * 8];
  const bfrag qf1 = *(const bfrag*)&Qb[(size_t)l15 * HDIM + 32 + lh * 8];

  const float c = 0.125f * 1.44269504089f;  // log2(e)/sqrt(HDIM)
  const int NT = S_LEN / 32;                // 64 tiles

  // ---- Pass 1: l[q] = sum_k exp2(s*c); S^T layout: lane q=l15, k=4*lh+r ----
  gload_lds16(Kb + (size_t)(0 * 32 + krow) * HDIM + kchk_s * 8, (char*)&Ks[0][0] + wid * 1024);
  gload_lds16(Kb + (size_t)(1 * 32 + krow) * HDIM + kchk_s * 8, (char*)&Ks[1][0] + wid * 1024);
  SBAR();
  asm volatile("s_waitcnt vmcnt(1)" ::: "memory");  // own g0 landed (qf over-waited)
  __builtin_amdgcn_s_barrier();
  SBAR();

  int cur = 0;
  float lr = 0.f;
  for (int t = 0; t < NT; ++t) {
    if (t + 2 < NT) {
      int s2 = cur + 2; if (s2 >= 3) s2 -= 3;
      gload_lds16(Kb + (size_t)((t + 2) * 32 + krow) * HDIM + kchk_s * 8,
                  (char*)&Ks[s2][0] + wid * 1024);
    }
    const bfrag ca0 = *(const bfrag*)&Ks[cur][l15 * 64 + ksw0];
    const bfrag ca1 = *(const bfrag*)&Ks[cur][l15 * 64 + ksw1];
    const bfrag cb0 = *(const bfrag*)&Ks[cur][(16 + l15) * 64 + ksw0];
    const bfrag cb1 = *(const bfrag*)&Ks[cur][(16 + l15) * 64 + ksw1];
    f32x4 sa = {}, sb = {};
    __builtin_amdgcn_s_setprio(1);
    sa = __builtin_amdgcn_mfma_f32_16x16x32_bf16(ca0, qf0, sa, 0, 0, 0);
    sa = __builtin_amdgcn_mfma_f32_16x16x32_bf16(ca1, qf1, sa, 0, 0, 0);
    sb = __builtin_amdgcn_mfma_f32_16x16x32_bf16(cb0, qf0, sb, 0, 0, 0);
    sb = __builtin_amdgcn_mfma_f32_16x16x32_bf16(cb1, qf1, sb, 0, 0, 0);
    __builtin_amdgcn_s_setprio(0);
#pragma unroll
    for (int r = 0; r < 4; ++r)
      lr += exp2f(sa[r] * c) + exp2f(sb[r] * c);
    if (t < NT - 1) {
      SBAR();
      if (t < NT - 2) asm volatile("s_waitcnt vmcnt(1)" ::: "memory");
      else            asm volatile("s_waitcnt vmcnt(0)" ::: "memory");
      __builtin_amdgcn_s_barrier();
      SBAR();
    }
    cur = cur + 1; if (cur >= 3) cur -= 3;
  }
  // lanes {l15, +16, +32, +48} hold partials of the same q row
  lr += __shfl_xor(lr, 16);
  lr += __shfl_xor(lr, 32);
  const float linv = __builtin_amdgcn_rcpf(lr);

  // ---- inter-pass barrier: pass-2 stage DMAs issued only after release ----
  SBAR();
  __builtin_amdgcn_s_barrier();
  SBAR();

  // ---- Pass 2: recompute, normalize, pool P, batched nt stores, PV ----
  f32x4 cacc[4] = {};

  gload_lds16(Kb + (size_t)(0 * 32 + krow) * HDIM + kchk_s * 8, (char*)&Ks[0][0] + wid * 1024);
  gload_lds16(Vb + (size_t)vrow * S_LEN + 0  + vchk_s * 8,      (char*)&Vs[0][0] + wid * 1024);
  gload_lds16(Kb + (size_t)(1 * 32 + krow) * HDIM + kchk_s * 8, (char*)&Ks[1][0] + wid * 1024);
  gload_lds16(Vb + (size_t)vrow * S_LEN + 32 + vchk_s * 8,      (char*)&Vs[1][0] + wid * 1024);
  SBAR();
  asm volatile("s_waitcnt vmcnt(2)" ::: "memory");  // own g0 pair landed; g1 in flight
  __builtin_amdgcn_s_barrier();
  SBAR();

  cur = 0;
  for (int t = 0; t < NT; ++t) {
    const int k0 = t * 32;
    if (t + 2 < NT) {
      int s2 = cur + 2; if (s2 >= 3) s2 -= 3;
      gload_lds16(Kb + (size_t)(k0 + 64 + krow) * HDIM + kchk_s * 8,
                  (char*)&Ks[s2][0] + wid * 1024);
      gload_lds16(Vb + (size_t)vrow * S_LEN + k0 + 64 + vchk_s * 8,
                  (char*)&Vs[s2][0] + wid * 1024);
    }
    const bfrag ca0 = *(const bfrag*)&Ks[cur][l15 * 64 + ksw0];
    const bfrag ca1 = *(const bfrag*)&Ks[cur][l15 * 64 + ksw1];
    const bfrag cb0 = *(const bfrag*)&Ks[cur][(16 + l15) * 64 + ksw0];
    const bfrag cb1 = *(const bfrag*)&Ks[cur][(16 + l15) * 64 + ksw1];
    const bfrag vf0 = *(const bfrag*)&Vs[cur][(0 * 16 + l15) * 32 + vsw];
    const bfrag vf1 = *(const bfrag*)&Vs[cur][(1 * 16 + l15) * 32 + vsw];
    const bfrag vf2 = *(const bfrag*)&Vs[cur][(2 * 16 + l15) * 32 + vsw];
    const bfrag vf3 = *(const bfrag*)&Vs[cur][(3 * 16 + l15) * 32 + vsw];

    f32x4 sa = {}, sb = {};
    __builtin_amdgcn_s_setprio(1);
    sa = __builtin_amdgcn_mfma_f32_16x16x32_bf16(ca0, qf0, sa, 0, 0, 0);
    sa = __builtin_amdgcn_mfma_f32_16x16x32_bf16(ca1, qf1, sa, 0, 0, 0);
    sb = __builtin_amdgcn_mfma_f32_16x16x32_bf16(cb0, qf0, sb, 0, 0, 0);
    sb = __builtin_amdgcn_mfma_f32_16x16x32_bf16(cb1, qf1, sb, 0, 0, 0);
    __builtin_amdgcn_s_setprio(0);

    f32x4 pa, pb;
#pragma unroll
    for (int r = 0; r < 4; ++r) pa[r] = exp2f(sa[r] * c) * linv;
#pragma unroll
    for (int r = 0; r < 4; ++r) pb[r] = exp2f(sb[r] * c) * linv;

    // pool P (f32, wave-private rows): parity halves of the 64-col pair window
    const int pcol = (t & 1) * 32;
    *(f32x4*)&Pool[wid][l15][pcol + lh * 4]      = pa;
    *(f32x4*)&Pool[wid][l15][pcol + 16 + lh * 4] = pb;

    u16x4 ua = {bfh(pa[0]), bfh(pa[1]), bfh(pa[2]), bfh(pa[3])};
    u16x4 ub = {bfh(pb[0]), bfh(pb[1]), bfh(pb[2]), bfh(pb[3])};
    *(u16x4*)&Plds[wid][l15][lh * 4]      = ua;
    *(u16x4*)&Plds[wid][l15][16 + lh * 4] = ub;

    const bfrag pf = *(const bfrag*)&Plds[wid][l15][lh * 8];
    __builtin_amdgcn_s_setprio(1);
    cacc[0] = __builtin_amdgcn_mfma_f32_16x16x32_bf16(pf, vf0, cacc[0], 0, 0, 0);
    cacc[1] = __builtin_amdgcn_mfma_f32_16x16x32_bf16(pf, vf1, cacc[1], 0, 0, 0);
    cacc[2] = __builtin_amdgcn_mfma_f32_16x16x32_bf16(pf, vf2, cacc[2], 0, 0, 0);
    cacc[3] = __builtin_amdgcn_mfma_f32_16x16x32_bf16(pf, vf3, cacc[3], 0, 0, 0);
    __builtin_amdgcn_s_setprio(0);

    if (t & 1) {
      // drain the wave's 16x64 P window as 4 nt stores (256B runs).
      const int kb = (t - 1) * 32;
#pragma unroll
      for (int i = 0; i < 4; ++i) {
        const int rw = i * 4 + (lane >> 4);            // row within wave slice
        const f32x4 v = *(const f32x4*)&Pool[wid][rw][(lane & 15) * 4];
        float* dst = attn + ((size_t)bh * S_LEN + q0 + wid * 16 + rw) * S_LEN +
                     kb + (lane & 15) * 4;
        __builtin_nontemporal_store(v, (f32x4*)dst);
      }
    }

    if (t < NT - 1) {
      SBAR();
      // newer-than-g_{t+1}: stores(4 per pair) + g_{t+2}(2) = 6 uniformly.
      if (t < NT - 2) asm volatile("s_waitcnt vmcnt(6)" ::: "memory");
      else            asm volatile("s_waitcnt vmcnt(4)" ::: "memory");
      __builtin_amdgcn_s_barrier();
      SBAR();
    }
    cur = cur + 1; if (cur >= 3) cur -= 3;
  }

  // ctx in [B,S,H*64] bf16 so the output GEMM reads contiguous rows
#pragma unroll
  for (int n = 0; n < 4; ++n) {
#pragma unroll
    for (int r = 0; r < 4; ++r) {
      const size_t tok = (size_t)b * S_LEN + q0 + wid * 16 + lh * 4 + r;
      ctx[tok * DMODEL + h * HDIM + n * 16 + l15] = f2bf(cacc[n][r]);
    }
  }
}

// ---------------------------------------------------------------------------
extern "C" void kernel_launch(void* const* d_in, const int* in_sizes, int n_in,
                              void* d_out, int out_size, void* d_ws, size_t ws_size,
                              hipStream_t stream) {
  const float* Xq = (const float*)d_in[0];
  const float* Xk = (const float*)d_in[1];
  const float* Xv = (const float*)d_in[2];
  const float* Wq = (const float*)d_in[3];
  const float* bq = (const float*)d_in[4];
  const float* Wk = (const float*)d_in[5];
  const float* bk = (const float*)d_in[6];
  const float* Wv = (const float*)d_in[7];
  const float* bv = (const float*)d_in[8];
  const float* Wo = (const float*)d_in[9];
  const float* bo = (const float*)d_in[10];

  float* out  = (float*)d_out;                       // [B,S,D]
  float* attn = out + (size_t)NTOK * DMODEL;         // [B,H,S,S]

  char* ws = (char*)d_ws;
  const size_t XB = (size_t)NTOK * DMODEL * 2;       // 16 MB bf16 activation
  const size_t WB = (size_t)DMODEL * DMODEL * 2;     // 2 MB bf16 weight
  ushort* xq  = (ushort*)(ws);
  ushort* xk  = (ushort*)(ws + XB);
  ushort* xv  = (ushort*)(ws + 2 * XB);
  ushort* wqt = (ushort*)(ws + 3 * XB);
  ushort* wkt = (ushort*)(ws + 3 * XB + WB);
  ushort* wvt = (ushort*)(ws + 3 * XB + 2 * WB);
  ushort* wot = (ushort*)(ws + 3 * XB + 3 * WB);
  ushort* qh  = (ushort*)(ws + 3 * XB + 4 * WB);          // [BH,S,64]
  ushort* kh  = (ushort*)(ws + 4 * XB + 4 * WB);
  ushort* vh  = (ushort*)(ws + 5 * XB + 4 * WB);
  ushort* vt  = (ushort*)(ws + 6 * XB + 4 * WB);          // [BH,64,S]
  ushort* ctx = (ushort*)(ws + 7 * XB + 4 * WB);          // [B,S,1024]

  // fused prep: QKV fp32->bf16 + all 4 weight transposes
  prep_kernel<<<dim3(1024, 4), 256, 0, stream>>>(
      Xq, Xk, Xv, xq, xk, xv, Wq, Wk, Wv, Wo, wqt, wkt, wvt, wot);

  // Q,K,V projections: M=8192, N=1024, K=1024, outputs scattered to head layout
  gemm_bt<1><<<dim3(64, 8, 3), 256, 0, stream>>>(
      xq, xk, xv, wqt, wkt, wvt, bq, bk, bv,
      (void*)qh, (void*)kh, (void*)vh, NTOK, DMODEL, DMODEL);

  vtrans<<<dim3(32, BHEADS), 256, 0, stream>>>(vh, vt);

  attn_kernel<<<dim3(S_LEN / 64 * BHEADS), 256, 0, stream>>>(qh, kh, vt, attn, ctx);

  // out = ctx @ Wo^T + bo (fp32 into d_out)
  gemm_bt<0><<<dim3(64, 8, 1), 256, 0, stream>>>(
      ctx, ctx, ctx, wot, wot, wot, bo, bo, bo,
      (void*)out, (void*)out, (void*)out, NTOK, DMODEL, DMODEL);
}

// Round 11
// 472.687 us; speedup vs baseline: 1.5674x; 1.0151x over previous
//
#include <hip/hip_runtime.h>
#include <hip/hip_bf16.h>
#include <math.h>

// Problem constants
#define S_LEN  2048
#define BATCH  4
#define NHEAD  16
#define HDIM   64
#define DMODEL 1024
#define NTOK   (BATCH * S_LEN)   // 8192 tokens
#define BHEADS (BATCH * NHEAD)   // 64

typedef __attribute__((ext_vector_type(8))) short bfrag;   // 8 bf16 (4 VGPRs) MFMA A/B frag
typedef __attribute__((ext_vector_type(4))) float f32x4;   // MFMA C/D frag
typedef __attribute__((ext_vector_type(4))) ushort u16x4;

__device__ inline ushort f2bf(float f) {
  union { float f; unsigned u; } v; v.f = f;
  unsigned r = (v.u + 0x7FFFu + ((v.u >> 16) & 1u)) >> 16;  // RNE
  return (ushort)r;
}

// 2-op bf16 round (half-up; differs from RNE only on exact ties)
__device__ inline ushort bfh(float f) {
  union { float f; unsigned u; } v; v.f = f;
  return (ushort)((v.u + 0x8000u) >> 16);
}

__device__ inline void gload_lds16(const void* g, void* lds) {
  __builtin_amdgcn_global_load_lds(
      (const __attribute__((address_space(1))) unsigned int*)g,
      (__attribute__((address_space(3))) unsigned int*)lds, 16, 0, 0);
}

#define SBAR() __builtin_amdgcn_sched_barrier(0)

// ---------------------------------------------------------------------------
// Fused prep: y in {0,1,2} -> fp32->bf16 convert of Q/K/V activations;
// y == 3 -> all four weight transposes (W [K][N] fp32 -> Wt [N][K] bf16).
__global__ __launch_bounds__(256) void prep_kernel(
    const float* xq, const float* xk, const float* xv,
    ushort* oq, ushort* ok, ushort* ov,
    const float* w0, const float* w1, const float* w2, const float* w3,
    ushort* t0, ushort* t1, ushort* t2, ushort* t3) {
  if (blockIdx.y < 3) {
    const float* src = (blockIdx.y == 0) ? xq : (blockIdx.y == 1) ? xk : xv;
    ushort* dst      = (blockIdx.y == 0) ? oq : (blockIdx.y == 1) ? ok : ov;
    const int n4 = NTOK * DMODEL / 4;
    for (int i = blockIdx.x * blockDim.x + threadIdx.x; i < n4;
         i += gridDim.x * blockDim.x) {
      float4 f = reinterpret_cast<const float4*>(src)[i];
      ushort4 o;
      o.x = f2bf(f.x); o.y = f2bf(f.y); o.z = f2bf(f.z); o.w = f2bf(f.w);
      reinterpret_cast<ushort4*>(dst)[i] = o;
    }
  } else {
    __shared__ float t[64][65];
    const int widx = blockIdx.x >> 8;          // which weight
    const int bx   = blockIdx.x & 255;
    const float* w = widx == 0 ? w0 : widx == 1 ? w1 : widx == 2 ? w2 : w3;
    ushort*     wt = widx == 0 ? t0 : widx == 1 ? t1 : widx == 2 ? t2 : t3;
    const int k0 = (bx >> 4) * 64;
    const int n0 = (bx & 15) * 64;
    for (int i = threadIdx.x; i < 4096; i += 256) {
      int r = i >> 6, c = i & 63;
      t[r][c] = w[(size_t)(k0 + r) * DMODEL + n0 + c];
    }
    __syncthreads();
    for (int i = threadIdx.x; i < 4096; i += 256) {
      int r = i >> 6, c = i & 63;
      wt[(size_t)(n0 + r) * DMODEL + k0 + c] = f2bf(t[c][r]);
    }
  }
}

// ---------------------------------------------------------------------------
// C = A[M,K] @ Bt[N,K]^T + bias.  128x128 tile, BK=32, 4 waves, 4x4 frags/wave.
// MODE 0: fp32 row-major [M,N] output (final projection into d_out)
// MODE 1: bf16 head-layout outputs. z<2 -> [B,H,S,64]; z==2 (V) -> transposed
//         [B,H,64,S] written directly (eliminates the separate vtrans pass).
template <int MODE>
__global__ __launch_bounds__(256) void gemm_bt(
    const ushort* A0, const ushort* A1, const ushort* A2,
    const ushort* B0, const ushort* B1, const ushort* B2,
    const float* c0, const float* c1, const float* c2,
    void* o0, void* o1, void* o2, int M, int N, int K) {
  const int z = blockIdx.z;
  const ushort* A  = z == 0 ? A0 : z == 1 ? A1 : A2;
  const ushort* Bt = z == 0 ? B0 : z == 1 ? B1 : B2;
  const float* bias = z == 0 ? c0 : z == 1 ? c1 : c2;
  void* dst = z == 0 ? o0 : z == 1 ? o1 : o2;

  __shared__ __align__(16) ushort As[128][32];
  __shared__ __align__(16) ushort Bs[128][32];
  const int tid  = threadIdx.x;
  const int wid  = tid >> 6;
  const int l15  = tid & 15;
  const int lh   = (tid & 63) >> 4;
  const int row0 = blockIdx.x * 128;
  const int col0 = blockIdx.y * 128;
  const int wr   = (wid >> 1) * 64;
  const int wc   = (wid & 1) * 64;

  f32x4 acc[4][4] = {};

  for (int kt = 0; kt < K; kt += 32) {
#pragma unroll
    for (int j = 0; j < 2; ++j) {
      const int toff = (j * 256 + tid) * 16;  // linear byte offset in the 8 KB tile
      const int r    = toff >> 6;             // 64 B per tile row
      const int cb   = toff & 63;
      gload_lds16(A + (size_t)(row0 + r) * K + kt + (cb >> 1),
                  (char*)(&As[0][0]) + (j * 256 + wid * 64) * 16);
      gload_lds16(Bt + (size_t)(col0 + r) * K + kt + (cb >> 1),
                  (char*)(&Bs[0][0]) + (j * 256 + wid * 64) * 16);
    }
    __syncthreads();
    bfrag av[4], bv[4];
#pragma unroll
    for (int m = 0; m < 4; ++m) av[m] = *(const bfrag*)&As[wr + m * 16 + l15][lh * 8];
#pragma unroll
    for (int n = 0; n < 4; ++n) bv[n] = *(const bfrag*)&Bs[wc + n * 16 + l15][lh * 8];
#pragma unroll
    for (int m = 0; m < 4; ++m)
#pragma unroll
      for (int n = 0; n < 4; ++n)
        acc[m][n] = __builtin_amdgcn_mfma_f32_16x16x32_bf16(av[m], bv[n], acc[m][n], 0, 0, 0);
    __syncthreads();
  }

#pragma unroll
  for (int m = 0; m < 4; ++m) {
#pragma unroll
    for (int n = 0; n < 4; ++n) {
#pragma unroll
      for (int r = 0; r < 4; ++r) {
        const int grow = row0 + wr + m * 16 + lh * 4 + r;   // token / output row
        const int gcol = col0 + wc + n * 16 + l15;          // output channel
        const float v = acc[m][n][r] + bias[gcol];
        if (MODE == 0) {
          ((float*)dst)[(size_t)grow * N + gcol] = v;
        } else if (z != 2) {
          // [B,H,S,64]: b = grow>>11, s = grow&2047, h = gcol>>6, dd = gcol&63
          const size_t o = (((size_t)(grow >> 11) * NHEAD + (gcol >> 6)) * S_LEN +
                            (grow & 2047)) * HDIM + (gcol & 63);
          ((ushort*)dst)[o] = f2bf(v);
        } else {
          // V: transposed head layout [B,H,64,S] (direct Vt write)
          const size_t o = (((size_t)(grow >> 11) * NHEAD + (gcol >> 6)) * HDIM +
                            (gcol & 63)) * S_LEN + (grow & 2047);
          ((ushort*)dst)[o] = f2bf(v);
        }
      }
    }
  }
}

// ---------------------------------------------------------------------------
// Fused attention (R8 structure, best known): wave-private f32 Pool batches P
// into 256B-run nontemporal stores (4 x dwordx4 per 2 k-tiles); nt keeps the
// 1.07GB write-once stream out of L2/L3 (R9 showed L2-routing thrashes -230us).
// Ring-3 K/V staging, counted vmcnt barriers.
__global__ __launch_bounds__(256) void attn_kernel(
    const ushort* Q, const ushort* K, const ushort* Vt, float* attn, ushort* ctx) {
  // XCD swizzle: all 32 q-tiles of one head on one XCD (K/V stay L2-resident)
  const int b0    = blockIdx.x;          // 0..2047
  const int xcd   = b0 & 7;
  const int inner = b0 >> 3;             // 0..255
  const int bh    = xcd + ((inner >> 5) << 3);   // batch*head 0..63
  const int qt    = inner & 31;
  const int b  = bh >> 4;
  const int h  = bh & 15;
  const int q0 = qt * 64;
  const int wid  = threadIdx.x >> 6;
  const int lane = threadIdx.x & 63;
  const int l15  = lane & 15;
  const int lh   = lane >> 4;

  const ushort* Qb = Q  + ((size_t)bh * S_LEN + q0 + wid * 16) * HDIM;
  const ushort* Kb = K  + (size_t)bh * S_LEN * HDIM;
  const ushort* Vb = Vt + (size_t)bh * HDIM * S_LEN;

  __shared__ __align__(16) ushort Ks[3][32 * 64];
  __shared__ __align__(16) ushort Vs[3][64 * 32];
  __shared__ __align__(16) ushort Plds[4][16][40];
  __shared__ __align__(16) float  Pool[4][16][66];   // per-wave P staging (f32)

  const int krow   = threadIdx.x >> 3;
  const int kchk_s = (threadIdx.x & 7) ^ (krow & 7);
  const int vrow   = threadIdx.x >> 2;
  const int vchk_s = (threadIdx.x & 3) ^ (vrow & 3);

  const int ksw0 = ((lh ^ (l15 & 7)) * 8);
  const int ksw1 = (((lh + 4) ^ (l15 & 7)) * 8);
  const int vsw  = ((lh ^ (l15 & 3)) * 8);

  const bfrag qf0 = *(const bfrag*)&Qb[(size_t)l15 * HDIM + lh * 8];
  const bfrag qf1 = *(const bfrag*)&Qb[(size_t)l15 * HDIM + 32 + lh * 8];

  const float c = 0.125f * 1.44269504089f;  // log2(e)/sqrt(HDIM)
  const int NT = S_LEN / 32;                // 64 tiles

  // ---- Pass 1: l[q] = sum_k exp2(s*c); S^T layout: lane q=l15, k=4*lh+r ----
  gload_lds16(Kb + (size_t)(0 * 32 + krow) * HDIM + kchk_s * 8, (char*)&Ks[0][0] + wid * 1024);
  gload_lds16(Kb + (size_t)(1 * 32 + krow) * HDIM + kchk_s * 8, (char*)&Ks[1][0] + wid * 1024);
  SBAR();
  asm volatile("s_waitcnt vmcnt(1)" ::: "memory");  // own g0 landed (qf over-waited)
  __builtin_amdgcn_s_barrier();
  SBAR();

  int cur = 0;
  float lr = 0.f;
  for (int t = 0; t < NT; ++t) {
    if (t + 2 < NT) {
      int s2 = cur + 2; if (s2 >= 3) s2 -= 3;
      gload_lds16(Kb + (size_t)((t + 2) * 32 + krow) * HDIM + kchk_s * 8,
                  (char*)&Ks[s2][0] + wid * 1024);
    }
    const bfrag ca0 = *(const bfrag*)&Ks[cur][l15 * 64 + ksw0];
    const bfrag ca1 = *(const bfrag*)&Ks[cur][l15 * 64 + ksw1];
    const bfrag cb0 = *(const bfrag*)&Ks[cur][(16 + l15) * 64 + ksw0];
    const bfrag cb1 = *(const bfrag*)&Ks[cur][(16 + l15) * 64 + ksw1];
    f32x4 sa = {}, sb = {};
    __builtin_amdgcn_s_setprio(1);
    sa = __builtin_amdgcn_mfma_f32_16x16x32_bf16(ca0, qf0, sa, 0, 0, 0);
    sa = __builtin_amdgcn_mfma_f32_16x16x32_bf16(ca1, qf1, sa, 0, 0, 0);
    sb = __builtin_amdgcn_mfma_f32_16x16x32_bf16(cb0, qf0, sb, 0, 0, 0);
    sb = __builtin_amdgcn_mfma_f32_16x16x32_bf16(cb1, qf1, sb, 0, 0, 0);
    __builtin_amdgcn_s_setprio(0);
#pragma unroll
    for (int r = 0; r < 4; ++r)
      lr += exp2f(sa[r] * c) + exp2f(sb[r] * c);
    if (t < NT - 1) {
      SBAR();
      if (t < NT - 2) asm volatile("s_waitcnt vmcnt(1)" ::: "memory");
      else            asm volatile("s_waitcnt vmcnt(0)" ::: "memory");
      __builtin_amdgcn_s_barrier();
      SBAR();
    }
    cur = cur + 1; if (cur >= 3) cur -= 3;
  }
  // lanes {l15, +16, +32, +48} hold partials of the same q row
  lr += __shfl_xor(lr, 16);
  lr += __shfl_xor(lr, 32);
  const float linv = __builtin_amdgcn_rcpf(lr);

  // ---- inter-pass barrier: pass-2 stage DMAs issued only after release ----
  SBAR();
  __builtin_amdgcn_s_barrier();
  SBAR();

  // ---- Pass 2: recompute, normalize, pool P, batched nt stores, PV ----
  f32x4 cacc[4] = {};

  gload_lds16(Kb + (size_t)(0 * 32 + krow) * HDIM + kchk_s * 8, (char*)&Ks[0][0] + wid * 1024);
  gload_lds16(Vb + (size_t)vrow * S_LEN + 0  + vchk_s * 8,      (char*)&Vs[0][0] + wid * 1024);
  gload_lds16(Kb + (size_t)(1 * 32 + krow) * HDIM + kchk_s * 8, (char*)&Ks[1][0] + wid * 1024);
  gload_lds16(Vb + (size_t)vrow * S_LEN + 32 + vchk_s * 8,      (char*)&Vs[1][0] + wid * 1024);
  SBAR();
  asm volatile("s_waitcnt vmcnt(2)" ::: "memory");  // own g0 pair landed; g1 in flight
  __builtin_amdgcn_s_barrier();
  SBAR();

  cur = 0;
  for (int t = 0; t < NT; ++t) {
    const int k0 = t * 32;
    if (t + 2 < NT) {
      int s2 = cur + 2; if (s2 >= 3) s2 -= 3;
      gload_lds16(Kb + (size_t)(k0 + 64 + krow) * HDIM + kchk_s * 8,
                  (char*)&Ks[s2][0] + wid * 1024);
      gload_lds16(Vb + (size_t)vrow * S_LEN + k0 + 64 + vchk_s * 8,
                  (char*)&Vs[s2][0] + wid * 1024);
    }
    const bfrag ca0 = *(const bfrag*)&Ks[cur][l15 * 64 + ksw0];
    const bfrag ca1 = *(const bfrag*)&Ks[cur][l15 * 64 + ksw1];
    const bfrag cb0 = *(const bfrag*)&Ks[cur][(16 + l15) * 64 + ksw0];
    const bfrag cb1 = *(const bfrag*)&Ks[cur][(16 + l15) * 64 + ksw1];
    const bfrag vf0 = *(const bfrag*)&Vs[cur][(0 * 16 + l15) * 32 + vsw];
    const bfrag vf1 = *(const bfrag*)&Vs[cur][(1 * 16 + l15) * 32 + vsw];
    const bfrag vf2 = *(const bfrag*)&Vs[cur][(2 * 16 + l15) * 32 + vsw];
    const bfrag vf3 = *(const bfrag*)&Vs[cur][(3 * 16 + l15) * 32 + vsw];

    f32x4 sa = {}, sb = {};
    __builtin_amdgcn_s_setprio(1);
    sa = __builtin_amdgcn_mfma_f32_16x16x32_bf16(ca0, qf0, sa, 0, 0, 0);
    sa = __builtin_amdgcn_mfma_f32_16x16x32_bf16(ca1, qf1, sa, 0, 0, 0);
    sb = __builtin_amdgcn_mfma_f32_16x16x32_bf16(cb0, qf0, sb, 0, 0, 0);
    sb = __builtin_amdgcn_mfma_f32_16x16x32_bf16(cb1, qf1, sb, 0, 0, 0);
    __builtin_amdgcn_s_setprio(0);

    f32x4 pa, pb;
#pragma unroll
    for (int r = 0; r < 4; ++r) pa[r] = exp2f(sa[r] * c) * linv;
#pragma unroll
    for (int r = 0; r < 4; ++r) pb[r] = exp2f(sb[r] * c) * linv;

    // pool P (f32, wave-private rows): parity halves of the 64-col pair window
    const int pcol = (t & 1) * 32;
    *(f32x4*)&Pool[wid][l15][pcol + lh * 4]      = pa;
    *(f32x4*)&Pool[wid][l15][pcol + 16 + lh * 4] = pb;

    u16x4 ua = {bfh(pa[0]), bfh(pa[1]), bfh(pa[2]), bfh(pa[3])};
    u16x4 ub = {bfh(pb[0]), bfh(pb[1]), bfh(pb[2]), bfh(pb[3])};
    *(u16x4*)&Plds[wid][l15][lh * 4]      = ua;
    *(u16x4*)&Plds[wid][l15][16 + lh * 4] = ub;

    const bfrag pf = *(const bfrag*)&Plds[wid][l15][lh * 8];
    __builtin_amdgcn_s_setprio(1);
    cacc[0] = __builtin_amdgcn_mfma_f32_16x16x32_bf16(pf, vf0, cacc[0], 0, 0, 0);
    cacc[1] = __builtin_amdgcn_mfma_f32_16x16x32_bf16(pf, vf1, cacc[1], 0, 0, 0);
    cacc[2] = __builtin_amdgcn_mfma_f32_16x16x32_bf16(pf, vf2, cacc[2], 0, 0, 0);
    cacc[3] = __builtin_amdgcn_mfma_f32_16x16x32_bf16(pf, vf3, cacc[3], 0, 0, 0);
    __builtin_amdgcn_s_setprio(0);

    if (t & 1) {
      // drain the wave's 16x64 P window as 4 nt stores (256B runs).
      const int kb = (t - 1) * 32;
#pragma unroll
      for (int i = 0; i < 4; ++i) {
        const int rw = i * 4 + (lane >> 4);            // row within wave slice
        const f32x4 v = *(const f32x4*)&Pool[wid][rw][(lane & 15) * 4];
        float* dst = attn + ((size_t)bh * S_LEN + q0 + wid * 16 + rw) * S_LEN +
                     kb + (lane & 15) * 4;
        __builtin_nontemporal_store(v, (f32x4*)dst);
      }
    }

    if (t < NT - 1) {
      SBAR();
      // newer-than-g_{t+1}: stores(4 per pair) + g_{t+2}(2) = 6 uniformly.
      if (t < NT - 2) asm volatile("s_waitcnt vmcnt(6)" ::: "memory");
      else            asm volatile("s_waitcnt vmcnt(4)" ::: "memory");
      __builtin_amdgcn_s_barrier();
      SBAR();
    }
    cur = cur + 1; if (cur >= 3) cur -= 3;
  }

  // ctx in [B,S,H*64] bf16 so the output GEMM reads contiguous rows
#pragma unroll
  for (int n = 0; n < 4; ++n) {
#pragma unroll
    for (int r = 0; r < 4; ++r) {
      const size_t tok = (size_t)b * S_LEN + q0 + wid * 16 + lh * 4 + r;
      ctx[tok * DMODEL + h * HDIM + n * 16 + l15] = f2bf(cacc[n][r]);
    }
  }
}

// ---------------------------------------------------------------------------
extern "C" void kernel_launch(void* const* d_in, const int* in_sizes, int n_in,
                              void* d_out, int out_size, void* d_ws, size_t ws_size,
                              hipStream_t stream) {
  const float* Xq = (const float*)d_in[0];
  const float* Xk = (const float*)d_in[1];
  const float* Xv = (const float*)d_in[2];
  const float* Wq = (const float*)d_in[3];
  const float* bq = (const float*)d_in[4];
  const float* Wk = (const float*)d_in[5];
  const float* bk = (const float*)d_in[6];
  const float* Wv = (const float*)d_in[7];
  const float* bv = (const float*)d_in[8];
  const float* Wo = (const float*)d_in[9];
  const float* bo = (const float*)d_in[10];

  float* out  = (float*)d_out;                       // [B,S,D]
  float* attn = out + (size_t)NTOK * DMODEL;         // [B,H,S,S]

  char* ws = (char*)d_ws;
  const size_t XB = (size_t)NTOK * DMODEL * 2;       // 16 MB bf16 activation
  const size_t WB = (size_t)DMODEL * DMODEL * 2;     // 2 MB bf16 weight
  ushort* xq  = (ushort*)(ws);
  ushort* xk  = (ushort*)(ws + XB);
  ushort* xv  = (ushort*)(ws + 2 * XB);
  ushort* wqt = (ushort*)(ws + 3 * XB);
  ushort* wkt = (ushort*)(ws + 3 * XB + WB);
  ushort* wvt = (ushort*)(ws + 3 * XB + 2 * WB);
  ushort* wot = (ushort*)(ws + 3 * XB + 3 * WB);
  ushort* qh  = (ushort*)(ws + 3 * XB + 4 * WB);          // [BH,S,64]
  ushort* kh  = (ushort*)(ws + 4 * XB + 4 * WB);
  ushort* vt  = (ushort*)(ws + 5 * XB + 4 * WB);          // [BH,64,S] (direct)
  ushort* ctx = (ushort*)(ws + 6 * XB + 4 * WB);          // [B,S,1024]

  // fused prep: QKV fp32->bf16 + all 4 weight transposes
  prep_kernel<<<dim3(1024, 4), 256, 0, stream>>>(
      Xq, Xk, Xv, xq, xk, xv, Wq, Wk, Wv, Wo, wqt, wkt, wvt, wot);

  // Q,K,V projections: M=8192, N=1024, K=1024. Q/K -> head layout [BH,S,64];
  // V (z==2) -> transposed head layout [BH,64,S] directly (vtrans eliminated).
  gemm_bt<1><<<dim3(64, 8, 3), 256, 0, stream>>>(
      xq, xk, xv, wqt, wkt, wvt, bq, bk, bv,
      (void*)qh, (void*)kh, (void*)vt, NTOK, DMODEL, DMODEL);

  attn_kernel<<<dim3(S_LEN / 64 * BHEADS), 256, 0, stream>>>(qh, kh, vt, attn, ctx);

  // out = ctx @ Wo^T + bo (fp32 into d_out)
  gemm_bt<0><<<dim3(64, 8, 1), 256, 0, stream>>>(
      ctx, ctx, ctx, wot, wot, wot, bo, bo, bo,
      (void*)out, (void*)out, (void*)out, NTOK, DMODEL, DMODEL);
}